// Round 10
// baseline (919.939 us; speedup 1.0000x reference)
//
#include <hip/hip_runtime.h>
#include <hip/hip_bf16.h>

namespace {

typedef _Float16 h16;
typedef _Float16 f16x8 __attribute__((ext_vector_type(8)));
typedef _Float16 f16x4 __attribute__((ext_vector_type(4)));
typedef float    f32x4 __attribute__((ext_vector_type(4)));

constexpr int T_SEQ = 512;
constexpr int B_SZ  = 1024;
constexpr int H_DIM = 128;
constexpr int ROWS  = 16;    // batch rows per block (MFMA N-tile)
constexpr int NT    = 512;   // 8 waves, 2/SIMD
constexpr int CH    = 4;     // K-chunks over a 128-dim operand
constexpr int CX    = 2;     // K-chunks over x (64)

// Frag-major LDS: slot = one f16x8 (16B) = what one lane reads for one chunk.
// frag[c][lane]: lane L=q'*16+lr' holds elements e -> k = c*32 + q'*8 + e of
// batch lr'. Reads are lane-linear 1KB contiguous => conflict-free.
constexpr int FH1 = 0;                 // h1-state frags [2][CH][64]
constexpr int FX  = 2 * CH * 64;       // x frags        [2][CX][64]
constexpr int FH2 = FX + 2 * CX * 64;  // h2-state frags [2][CH][64]
constexpr int NSLOT = FH2 + 2 * CH * 64;  // 1280 slots = 20 KB

// Fused 2-layer GRU, one block per 16 batch rows, 513 step-slots.
// Step g: bh = h1(g-1) frags. l0 computes h1(g) (own recurrence, K=192) AND
// xg1(g-1) = h1(g-1)@w_ih1^T on the SAME bh frags (12 extra MFMAs, zero extra
// LDS). xg1's D-layout == l1's C-init layout (lane: batch=lr, gates j0+i), so
// it passes to l1 in registers. l1 computes h2(g-1) from {h2(g-2) frags, xg1}.
// Frag convention verified on HW (rounds 4-9, absmax 1.2e-4):
//  A row = lane&15 (gate in tile), k = (lane>>4)*8 + e + 32*ks
//  B col = lane&15 (batch), same k;  D: col = lane&15, row = (lane>>4)*4 + i
__global__ __launch_bounds__(NT, 1)
void gru2(const float* __restrict__ x,      // [B][T][64] f32
          const float* __restrict__ w_ih0,  // [384][64]
          const float* __restrict__ w_hh0,  // [384][128]
          const float* __restrict__ b_ih0, const float* __restrict__ b_hh0,
          const float* __restrict__ w_ih1,  // [384][128]
          const float* __restrict__ w_hh1,  // [384][128]
          const float* __restrict__ b_ih1, const float* __restrict__ b_hh1,
          float* __restrict__ h2out)        // [B][128]
{
  __shared__ __align__(16) h16 lds[NSLOT * 8];

  const int tid = threadIdx.x;
  const int wv  = tid >> 6;        // wave 0..7
  const int ln  = tid & 63;
  const int q   = ln >> 4;
  const int lr  = ln & 15;
  const int r0  = blockIdx.x * ROWS;
  const int j0  = wv * 16 + q * 4;

  // gate-update write slot: element (batch=lr, gates j0..j0+3) in frag-major
  const int slotH = (wv >> 1) * 64 + ((wv & 1) * 2 + (q >> 1)) * 16 + lr;
  const int e0    = (q & 1) * 4;   // h16 element offset within the f16x8 slot

  auto ldw = [](const float* pw) {
    const float4 v0 = *(const float4*)(pw);
    const float4 v1 = *(const float4*)(pw + 4);
    f16x8 f;
    f[0]=(h16)v0.x; f[1]=(h16)v0.y; f[2]=(h16)v0.z; f[3]=(h16)v0.w;
    f[4]=(h16)v1.x; f[5]=(h16)v1.y; f[6]=(h16)v1.z; f[7]=(h16)v1.w;
    return f;
  };

  // ---- weights -> fp16 MFMA A-frags ----
  f16x8 wA0[3][CH], wB0[3][CX], wI1[3][CH], wA1[3][CH];
  #pragma unroll
  for (int p = 0; p < 3; ++p) {
    const int g = p * H_DIM + wv * 16 + lr;
    #pragma unroll
    for (int ks = 0; ks < CH; ++ks) {
      wA0[p][ks] = ldw(w_hh0 + (size_t)g * H_DIM + ks * 32 + q * 8);
      wI1[p][ks] = ldw(w_ih1 + (size_t)g * H_DIM + ks * 32 + q * 8);
      wA1[p][ks] = ldw(w_hh1 + (size_t)g * H_DIM + ks * 32 + q * 8);
    }
    #pragma unroll
    for (int ks = 0; ks < CX; ++ks)
      wB0[p][ks] = ldw(w_ih0 + (size_t)g * 64 + ks * 32 + q * 8);
  }

  // ---- biases folded into MFMA C-init ----
  f32x4 bR0, bZ0, bNx0, bNh0, bR1, bZ1, bNx1, bNh1;
  {
    auto mkb = [&](const float* bi, const float* bh,
                   f32x4& bR, f32x4& bZ, f32x4& bNx, f32x4& bNh) {
      const float4 ir  = *(const float4*)&bi[j0];
      const float4 hr  = *(const float4*)&bh[j0];
      const float4 iz  = *(const float4*)&bi[H_DIM + j0];
      const float4 hz  = *(const float4*)&bh[H_DIM + j0];
      const float4 in_ = *(const float4*)&bi[2 * H_DIM + j0];
      const float4 hn  = *(const float4*)&bh[2 * H_DIM + j0];
      bR[0]=ir.x+hr.x; bR[1]=ir.y+hr.y; bR[2]=ir.z+hr.z; bR[3]=ir.w+hr.w;
      bZ[0]=iz.x+hz.x; bZ[1]=iz.y+hz.y; bZ[2]=iz.z+hz.z; bZ[3]=iz.w+hz.w;
      bNx[0]=in_.x; bNx[1]=in_.y; bNx[2]=in_.z; bNx[3]=in_.w;
      bNh[0]=hn.x;  bNh[1]=hn.y;  bNh[2]=hn.z;  bNh[3]=hn.w;
    };
    mkb(b_ih0, b_hh0, bR0, bZ0, bNx0, bNh0);
    mkb(b_ih1, b_hh1, bR1, bZ1, bNx1, bNh1);
  }

  // ---- x staging: thread st<128 owns frag (chunk sc, lane sl) directly ----
  const int  sc  = tid >> 6;        // x-chunk (0..1) for tid<128
  const int  sl  = tid & 63;        // destination frag-lane
  const bool stg = (tid < CX * 64);
  const size_t xrow = (size_t)(r0 + (sl & 15)) * T_SEQ;
  const int    xk   = (sl >> 4) * 8 + sc * 32;

  auto load_x = [&](int t, f16x8& d) {
    if (stg) {
      const float* p = x + (xrow + t) * 64 + xk;   // 8 consecutive f32 = 32B
      const float4 v0 = *(const float4*)(p);
      const float4 v1 = *(const float4*)(p + 4);
      d[0]=(h16)v0.x; d[1]=(h16)v0.y; d[2]=(h16)v0.z; d[3]=(h16)v0.w;
      d[4]=(h16)v1.x; d[5]=(h16)v1.y; d[6]=(h16)v1.z; d[7]=(h16)v1.w;
    }
  };
  auto stage_x = [&](int buf, const f16x8& s) {
    if (stg) *(f16x8*)&lds[(FX + buf * CX * 64 + sc * 64 + sl) * 8] = s;
  };
  auto rd = [&](int cb) {   // read this lane's frag of chunk-base cb
    return *(const f16x8*)&lds[(cb + ln) * 8];
  };

  // ---- prologue: zero h-frags (h1 buf0, h2 buf1), stage x(0), load x(1) ----
  {
    f16x8 z; z[0]=z[1]=z[2]=z[3]=z[4]=z[5]=z[6]=z[7] = (h16)0.f;
    if (tid < 256) *(f16x8*)&lds[(FH1 + tid) * 8] = z;
    else           *(f16x8*)&lds[(FH2 + 256 + (tid - 256)) * 8] = z;
  }
  f16x8 s0; load_x(0, s0); stage_x(0, s0);
  f16x8 sA; load_x(1, sA);
  f16x8 sB;
  f16x4 h_old0, h_old1;
  h_old0[0]=h_old0[1]=h_old0[2]=h_old0[3] = (h16)0.f;
  h_old1 = h_old0;
  __syncthreads();

  f32x4 xR, xZ, xN;   // xg1 carry (l0 -> l1, same step, same lane)

  auto gates = [&](const f32x4& aR, const f32x4& aZ, const f32x4& aNx,
                   const f32x4& aNh, f16x4& h_old, float* hnv) -> f16x4 {
    f16x4 nv4;
    #pragma unroll
    for (int i = 0; i < 4; ++i) {
      const float rg = __builtin_amdgcn_rcpf(1.f + __expf(-aR[i]));
      const float zg = __builtin_amdgcn_rcpf(1.f + __expf(-aZ[i]));
      const float na = aNx[i] + rg * aNh[i];
      const float e2 = __expf(2.f * na);
      const float ng = 1.f - 2.f * __builtin_amdgcn_rcpf(e2 + 1.f);
      const float ho = (float)h_old[i];
      const float hn = ng + zg * (ho - ng);
      hnv[i] = hn;
      nv4[i] = (h16)hn;
    }
    h_old = nv4;
    return nv4;
  };

  // xg1: l1's input GEMM on l0's B-frags; result stays in registers
  auto xg_calc = [&](const f16x8* bh) {
    xR = bR1; xZ = bZ1; xN = bNx1;
    #pragma unroll
    for (int ks = 0; ks < CH; ++ks) {
      xR = __builtin_amdgcn_mfma_f32_16x16x32_f16(wI1[0][ks], bh[ks], xR, 0, 0, 0);
      xZ = __builtin_amdgcn_mfma_f32_16x16x32_f16(wI1[1][ks], bh[ks], xZ, 0, 0, 0);
      xN = __builtin_amdgcn_mfma_f32_16x16x32_f16(wI1[2][ks], bh[ks], xN, 0, 0, 0);
    }
  };

  auto l0_step = [&](int g, int cur, f16x8& s_use, f16x8& s_load, const f16x8* bh) {
    f16x8 bx[CX];
    #pragma unroll
    for (int c = 0; c < CX; ++c) bx[c] = rd(FX + cur * CX * 64 + c * 64);

    load_x((g + 2 < T_SEQ) ? g + 2 : T_SEQ - 1, s_load);

    f32x4 aR = bR0, aZ = bZ0, aNh = bNh0, aNx = bNx0;
    #pragma unroll
    for (int ks = 0; ks < CH; ++ks) {
      aR  = __builtin_amdgcn_mfma_f32_16x16x32_f16(wA0[0][ks], bh[ks], aR, 0, 0, 0);
      aZ  = __builtin_amdgcn_mfma_f32_16x16x32_f16(wA0[1][ks], bh[ks], aZ, 0, 0, 0);
      aNh = __builtin_amdgcn_mfma_f32_16x16x32_f16(wA0[2][ks], bh[ks], aNh, 0, 0, 0);
    }
    #pragma unroll
    for (int c = 0; c < CX; ++c) {
      aR  = __builtin_amdgcn_mfma_f32_16x16x32_f16(wB0[0][c], bx[c], aR, 0, 0, 0);
      aZ  = __builtin_amdgcn_mfma_f32_16x16x32_f16(wB0[1][c], bx[c], aZ, 0, 0, 0);
      aNx = __builtin_amdgcn_mfma_f32_16x16x32_f16(wB0[2][c], bx[c], aNx, 0, 0, 0);
    }
    xg_calc(bh);   // independent chains, same bh

    float hnv[4];
    const f16x4 nv4 = gates(aR, aZ, aNx, aNh, h_old0, hnv);
    *(f16x4*)&lds[(FH1 + (cur ^ 1) * 256 + slotH) * 8 + e0] = nv4;
    stage_x(cur ^ 1, s_use);
  };

  auto l1_step = [&](int cur, bool fin) {
    f16x8 bh2[CH];
    #pragma unroll
    for (int ks = 0; ks < CH; ++ks) bh2[ks] = rd(FH2 + cur * 256 + ks * 64);

    f32x4 aR = xR, aZ = xZ, aNh = bNh1;
    #pragma unroll
    for (int ks = 0; ks < CH; ++ks) {
      aR  = __builtin_amdgcn_mfma_f32_16x16x32_f16(wA1[0][ks], bh2[ks], aR, 0, 0, 0);
      aZ  = __builtin_amdgcn_mfma_f32_16x16x32_f16(wA1[1][ks], bh2[ks], aZ, 0, 0, 0);
      aNh = __builtin_amdgcn_mfma_f32_16x16x32_f16(wA1[2][ks], bh2[ks], aNh, 0, 0, 0);
    }
    float hnv[4];
    const f16x4 nv4 = gates(aR, aZ, xN, aNh, h_old1, hnv);
    *(f16x4*)&lds[(FH2 + (cur ^ 1) * 256 + slotH) * 8 + e0] = nv4;
    if (fin)
      *(float4*)&h2out[(size_t)(r0 + lr) * H_DIM + j0] =
          make_float4(hnv[0], hnv[1], hnv[2], hnv[3]);
  };

  // ---- pipeline: g=0 (l0); g=1..511 (l0+l1); g=512 (l1 final) ----
  {
    f16x8 bh[CH];
    #pragma unroll
    for (int ks = 0; ks < CH; ++ks) bh[ks] = rd(FH1 + 0 + ks * 64);
    l0_step(0, 0, sA, sB, bh);
  }
  __syncthreads();
  {
    f16x8 bh[CH];
    #pragma unroll
    for (int ks = 0; ks < CH; ++ks) bh[ks] = rd(FH1 + 256 + ks * 64);
    l0_step(1, 1, sB, sA, bh);
    l1_step(1, false);
  }
  __syncthreads();

  #pragma unroll 1
  for (int k = 1; k <= 255; ++k) {          // g = 2..511
    {
      f16x8 bh[CH];
      #pragma unroll
      for (int ks = 0; ks < CH; ++ks) bh[ks] = rd(FH1 + 0 + ks * 64);
      l0_step(2 * k, 0, sA, sB, bh);
      l1_step(0, false);
    }
    __syncthreads();
    {
      f16x8 bh[CH];
      #pragma unroll
      for (int ks = 0; ks < CH; ++ks) bh[ks] = rd(FH1 + 256 + ks * 64);
      l0_step(2 * k + 1, 1, sB, sA, bh);
      l1_step(1, false);
    }
    __syncthreads();
  }

  {   // g = 512: xg1(511) from h1(511) frags (buf0), l1 computes h2(511)
    f16x8 bh[CH];
    #pragma unroll
    for (int ks = 0; ks < CH; ++ks) bh[ks] = rd(FH1 + 0 + ks * 64);
    xg_calc(bh);
    l1_step(0, true);
  }
}

// FC head: out = fc2( BN( relu( fc1(h2_last) ) ) ); one row per block.
__global__ __launch_bounds__(64)
void head_kernel(const float* __restrict__ h2,
                 const float* __restrict__ fc1_w, const float* __restrict__ fc1_b,
                 const float* __restrict__ fc2_w, const float* __restrict__ fc2_b,
                 const float* __restrict__ gamma, const float* __restrict__ beta,
                 const float* __restrict__ mean,  const float* __restrict__ var,
                 float* __restrict__ out)
{
  const int row = blockIdx.x;
  const int j   = threadIdx.x;
  __shared__ __align__(16) float hrow[H_DIM];
  __shared__ __align__(16) float act[64];

  hrow[j]      = h2[(size_t)row * H_DIM + j];
  hrow[64 + j] = h2[(size_t)row * H_DIM + 64 + j];
  __syncthreads();

  float s = fc1_b[j];
  const float4* wr = reinterpret_cast<const float4*>(fc1_w + (size_t)j * H_DIM);
  #pragma unroll
  for (int k4 = 0; k4 < H_DIM / 4; ++k4) {
    const float4 w = wr[k4];
    const float4 h = reinterpret_cast<const float4*>(hrow)[k4];
    s += w.x * h.x + w.y * h.y + w.z * h.z + w.w * h.w;
  }
  s = fmaxf(s, 0.f);
  s = (s - mean[j]) * rsqrtf(var[j] + 1e-5f) * gamma[j] + beta[j];
  act[j] = s;
  __syncthreads();

  if (j < 2) {
    float o = fc2_b[j];
    #pragma unroll
    for (int k = 0; k < 64; ++k) o += fc2_w[(size_t)j * 64 + k] * act[k];
    out[(size_t)row * 2 + j] = o;
  }
}

} // namespace

extern "C" void kernel_launch(void* const* d_in, const int* in_sizes, int n_in,
                              void* d_out, int out_size, void* d_ws, size_t ws_size,
                              hipStream_t stream) {
  const float* x     = (const float*)d_in[0];
  const float* w_ih0 = (const float*)d_in[1];
  const float* w_hh0 = (const float*)d_in[2];
  const float* b_ih0 = (const float*)d_in[3];
  const float* b_hh0 = (const float*)d_in[4];
  const float* w_ih1 = (const float*)d_in[5];
  const float* w_hh1 = (const float*)d_in[6];
  const float* b_ih1 = (const float*)d_in[7];
  const float* b_hh1 = (const float*)d_in[8];
  const float* fc1_w = (const float*)d_in[9];
  const float* fc1_b = (const float*)d_in[10];
  const float* fc2_w = (const float*)d_in[11];
  const float* fc2_b = (const float*)d_in[12];
  const float* gamma = (const float*)d_in[13];
  const float* beta  = (const float*)d_in[14];
  const float* mean  = (const float*)d_in[15];
  const float* var   = (const float*)d_in[16];
  float* out = (float*)d_out;

  const size_t h2_bytes = (size_t)B_SZ * H_DIM * sizeof(float);  // 512 KB
  if (ws_size < h2_bytes) return;  // fail visibly
  float* h2 = (float*)d_ws;

  gru2<<<dim3(B_SZ / ROWS), dim3(NT), 0, stream>>>(
      x, w_ih0, w_hh0, b_ih0, b_hh0, w_ih1, w_hh1, b_ih1, b_hh1, h2);
  head_kernel<<<dim3(B_SZ), dim3(64), 0, stream>>>(
      h2, fc1_w, fc1_b, fc2_w, fc2_b, gamma, beta, mean, var, out);
}